// Round 1
// 345.056 us; speedup vs baseline: 1.1307x; 1.1307x over previous
//
#include <hip/hip_runtime.h>
#include <hip/hip_fp16.h>

// AxialAttention on MI355X (gfx950).
// x: [8,128,128,128] fp32, attend along H. Problem = (n0,h,w): S=128, d=16.
// K0 (prep): Wo fp32 -> bf16 (16K elems, trivial).
// K1 (attn): per-problem attention. K/V staged in LDS as f16 (8 KiB/problem ->
//            16 KiB/block -> 10 blocks/CU LDS ceiling, ~2x occupancy) and
//            consumed via v_fma_mix_f32 (f16 operand, f32 accumulate, full rate,
//            no unpack VALU). AO written as bf16 [b=(n0,w)][s][c] (MFMA-ready).
// K2 (proj): out[e][s][w] = Wo[e][c] . AO[w][s][c] + bo, as bf16 MFMA
//            16x16x32. Both fragments are 16B-contiguous global reads
//            (A: 8 consecutive c of a Wo row; B: 8 consecutive c of an AO row)
//            -> no LDS, no barriers; fp32 epilogue.

#define SEQ 128
#define HD 16

typedef __attribute__((ext_vector_type(8))) short bf16x8;
typedef __attribute__((ext_vector_type(4))) float f32x4;

// acc += f16(pk.lo/hi) * f   (f32 accumulate, VOP3P mixed fma)
#define FMX_LO(acc, pk, f) asm("v_fma_mix_f32 %0, %1, %2, %0 op_sel:[0,0,0] op_sel_hi:[1,0,0]" : "+v"(acc) : "v"(pk), "v"(f))
#define FMX_HI(acc, pk, f) asm("v_fma_mix_f32 %0, %1, %2, %0 op_sel:[1,0,0] op_sel_hi:[1,0,0]" : "+v"(acc) : "v"(pk), "v"(f))

__device__ __forceinline__ unsigned int bf16_rne(float x) {
    unsigned int u = __float_as_uint(x);
    return (u + 0x7fffu + ((u >> 16) & 1u)) >> 16;
}
__device__ __forceinline__ unsigned int pack_bf16(float a, float b) {
    return bf16_rne(a) | (bf16_rne(b) << 16);
}
__device__ __forceinline__ unsigned int pack_half2(float a, float b) {
    __half2 h = __floats2half2_rn(a, b);
    return *reinterpret_cast<unsigned int*>(&h);
}

__global__ void axattn_prep(const float* __restrict__ Wo,
                            unsigned short* __restrict__ Wob) {
    int i = blockIdx.x * 256 + threadIdx.x;   // 64 blocks * 256 = 16384
    Wob[i] = (unsigned short)bf16_rne(Wo[i]);
}

__global__ __launch_bounds__(128) void axattn_attn(
    const float* __restrict__ x,
    const float* __restrict__ Wq,
    const float* __restrict__ Wk,
    const float* __restrict__ Wv,
    unsigned short* __restrict__ AO)   // bf16 [(n0*128+w)][s][c]
{
    // bb = k*8 + xcd ; k = (n0*8 + h)*8 + wm ; w = xcd*16 + wm*2 + wave
    // 8 consecutive-k blocks on one XCD share each 64B x-line (L2 reuse).
    int bb  = blockIdx.x;
    int xcd = bb & 7;
    int k   = bb >> 3;
    int wm  = k & 7;
    int nh  = k >> 3;          // n0*8 + h
    int n0  = nh >> 3;
    int h   = nh & 7;
    int wi  = threadIdx.x >> 6;   // wave 0/1 -> own problem
    int t   = threadIdx.x & 63;
    int w   = xcd * 16 + wm * 2 + wi;

    // f16 K/V: [wave][row][8 dwords of half2] = 8 KiB per problem
    __shared__ unsigned int kbuf[2][SEQ][8];
    __shared__ unsigned int vbuf[2][SEQ][8];

    const float inv_scale = 0.088388347648318447f;  // 1/sqrt(128)

    float q[2][HD];
    #pragma unroll
    for (int r = 0; r < 2; ++r) {
        int row = t + 64 * r;
        const float* xp = x + ((size_t)(n0 * 128 + h * 16) * 128 + row) * 128 + w;
        float yv[HD];
        #pragma unroll
        for (int d = 0; d < HD; ++d) yv[d] = xp[(size_t)d * 16384];
        float qq[HD], kk[HD], vv[HD];
        #pragma unroll
        for (int e = 0; e < HD; ++e) { qq[e] = 0.f; kk[e] = 0.f; vv[e] = 0.f; }
        #pragma unroll
        for (int d = 0; d < HD; ++d) {
            float yd = yv[d];
            #pragma unroll
            for (int e = 0; e < HD; ++e) {
                qq[e] = fmaf(yd, Wq[e * HD + d], qq[e]);
                kk[e] = fmaf(yd, Wk[e * HD + d], kk[e]);
                vv[e] = fmaf(yd, Wv[e * HD + d], vv[e]);
            }
        }
        unsigned int kp[8], vp[8];
        #pragma unroll
        for (int d = 0; d < 8; ++d) {
            kp[d] = pack_half2(kk[2 * d], kk[2 * d + 1]);
            vp[d] = pack_half2(vv[2 * d], vv[2 * d + 1]);
        }
        *(uint4*)&kbuf[wi][row][0] = make_uint4(kp[0], kp[1], kp[2], kp[3]);
        *(uint4*)&kbuf[wi][row][4] = make_uint4(kp[4], kp[5], kp[6], kp[7]);
        *(uint4*)&vbuf[wi][row][0] = make_uint4(vp[0], vp[1], vp[2], vp[3]);
        *(uint4*)&vbuf[wi][row][4] = make_uint4(vp[4], vp[5], vp[6], vp[7]);
        #pragma unroll
        for (int e = 0; e < HD; ++e) q[r][e] = qq[e] * inv_scale;
    }
    __syncthreads();

    float l0 = 0.f, l1 = 0.f;
    float acc0[HD], acc1[HD];
    #pragma unroll
    for (int e = 0; e < HD; ++e) { acc0[e] = 0.f; acc1[e] = 0.f; }

    const uint4* k4 = (const uint4*)&kbuf[wi][0][0];
    const uint4* v4 = (const uint4*)&vbuf[wi][0][0];
    #pragma unroll 2
    for (int j = 0; j < SEQ; ++j) {
        uint4 ka = k4[2 * j + 0];
        uint4 kb = k4[2 * j + 1];
        unsigned int kw[8] = {ka.x, ka.y, ka.z, ka.w, kb.x, kb.y, kb.z, kb.w};
        float e0 = 0.f, e1 = 0.f;
        #pragma unroll
        for (int d = 0; d < 8; ++d) {
            FMX_LO(e0, kw[d], q[0][2 * d]);
            FMX_HI(e0, kw[d], q[0][2 * d + 1]);
            FMX_LO(e1, kw[d], q[1][2 * d]);
            FMX_HI(e1, kw[d], q[1][2 * d + 1]);
        }
        float p0 = __expf(e0);
        float p1 = __expf(e1);
        l0 += p0; l1 += p1;
        uint4 va = v4[2 * j + 0];
        uint4 vb = v4[2 * j + 1];
        unsigned int vw[8] = {va.x, va.y, va.z, va.w, vb.x, vb.y, vb.z, vb.w};
        #pragma unroll
        for (int d = 0; d < 8; ++d) {
            FMX_LO(acc0[2 * d],     vw[d], p0);
            FMX_HI(acc0[2 * d + 1], vw[d], p0);
            FMX_LO(acc1[2 * d],     vw[d], p1);
            FMX_HI(acc1[2 * d + 1], vw[d], p1);
        }
    }

    float rl0 = 1.f / l0;
    float rl1 = 1.f / l1;
    size_t base = ((size_t)(n0 * 128 + w) * 128) * 128 + h * 16;  // bf16 elems
    unsigned int o[8];
    #pragma unroll
    for (int d = 0; d < 8; ++d)
        o[d] = pack_bf16(acc0[2 * d] * rl0, acc0[2 * d + 1] * rl0);
    uint4* op = (uint4*)(AO + base + (size_t)t * 128);
    op[0] = make_uint4(o[0], o[1], o[2], o[3]);
    op[1] = make_uint4(o[4], o[5], o[6], o[7]);
    #pragma unroll
    for (int d = 0; d < 8; ++d)
        o[d] = pack_bf16(acc1[2 * d] * rl1, acc1[2 * d + 1] * rl1);
    op = (uint4*)(AO + base + (size_t)(t + 64) * 128);
    op[0] = make_uint4(o[0], o[1], o[2], o[3]);
    op[1] = make_uint4(o[4], o[5], o[6], o[7]);
}

// MFMA out-proj. Block = (n0, s, w-half). 4 waves; wave wv owns e-tile
// [wv*32, wv*32+32) x w-tile [wh*64, wh*64+64). m=e, n=w, k=c.
// A-frag: Wo_bf16[e][c], lane row e=l&15, k = (l>>4)*8 + 0..7 (contiguous c).
// B-frag: AO_bf16[(n0,w)][s][c], lane col w=l&15, same contiguous k=c.
// D-frag: col w = l&15, row e = (l>>4)*4 + r.
__global__ __launch_bounds__(256) void axattn_proj(
    const unsigned short* __restrict__ AOb,
    const unsigned short* __restrict__ Wob,
    const float* __restrict__ bo,
    float* __restrict__ out)
{
    int bb = blockIdx.x;
    int wh = bb & 1;
    int s  = (bb >> 1) & 127;
    int n0 = bb >> 8;
    int wv = threadIdx.x >> 6;
    int l  = threadIdx.x & 63;
    int lr = l & 15;
    int lk = (l >> 4) * 8;
    int eb = wv * 32;

    f32x4 acc[2][4];
    #pragma unroll
    for (int mi = 0; mi < 2; ++mi)
        #pragma unroll
        for (int ni = 0; ni < 4; ++ni)
            acc[mi][ni] = (f32x4){0.f, 0.f, 0.f, 0.f};

    const unsigned short* wp = Wob + (size_t)(eb + lr) * 128 + lk;
    const unsigned short* ap = AOb
        + ((size_t)(n0 * 128 + wh * 64 + lr) * 128 + s) * 128 + lk;

    #pragma unroll
    for (int ct = 0; ct < 4; ++ct) {             // k = c tile of 32
        bf16x8 a0 = *(const bf16x8*)(wp + ct * 32);
        bf16x8 a1 = *(const bf16x8*)(wp + 16 * 128 + ct * 32);
        #pragma unroll
        for (int ni = 0; ni < 4; ++ni) {
            bf16x8 bf = *(const bf16x8*)(ap + (size_t)ni * 262144 + ct * 32);
            acc[0][ni] = __builtin_amdgcn_mfma_f32_16x16x32_bf16(a0, bf, acc[0][ni], 0, 0, 0);
            acc[1][ni] = __builtin_amdgcn_mfma_f32_16x16x32_bf16(a1, bf, acc[1][ni], 0, 0, 0);
        }
    }

    int r4 = (l >> 4) * 4;
    #pragma unroll
    for (int mi = 0; mi < 2; ++mi) {
        #pragma unroll
        for (int r = 0; r < 4; ++r) {
            int e = eb + mi * 16 + r4 + r;
            float bv = bo[e];
            float* orow = out + ((size_t)(n0 * 128 + e) * 128 + s) * 128 + wh * 64 + lr;
            #pragma unroll
            for (int ni = 0; ni < 4; ++ni)
                orow[ni * 16] = acc[mi][ni][r] + bv;
        }
    }
}

extern "C" void kernel_launch(void* const* d_in, const int* in_sizes, int n_in,
                              void* d_out, int out_size, void* d_ws, size_t ws_size,
                              hipStream_t stream) {
    const float* x  = (const float*)d_in[0];
    const float* Wq = (const float*)d_in[1];
    const float* Wk = (const float*)d_in[2];
    const float* Wv = (const float*)d_in[3];
    const float* Wo = (const float*)d_in[4];
    const float* bo = (const float*)d_in[5];
    float* out = (float*)d_out;

    unsigned short* AOb = (unsigned short*)d_ws;                        // 32 MiB bf16
    unsigned short* Wob = (unsigned short*)((char*)d_ws + (32u << 20)); // 32 KiB bf16

    axattn_prep<<<64, 256, 0, stream>>>(Wo, Wob);
    axattn_attn<<<4096, 128, 0, stream>>>(x, Wq, Wk, Wv, AOb);
    axattn_proj<<<2048, 256, 0, stream>>>(AOb, Wob, bo, out);
}

// Round 3
// 200.600 us; speedup vs baseline: 1.9449x; 1.7201x over previous
//
#include <hip/hip_runtime.h>
#include <hip/hip_fp16.h>

// AxialAttention on MI355X (gfx950).
// x: [8,128,128,128] fp32, attend along H. Problem = (n0,h,w): S=128, d=16.
// K1 (attn): fully-MFMA, LDS-free. 1 wave = 1 problem. All fragments chain
//   in-register via the D==A/B layout identity of 16x16x16 MFMA:
//     Q^T = mfma(Wq, y^T)  -> B-frag of S-mfma   (scaled by 1/sqrt(128)*log2e)
//     K^T = mfma(Wk, y^T)  -> A-frag of S-mfma
//     V   = mfma(y, Wv^T)  -> B-frag of PV-mfma
//     P^T = exp2(mfma(K, Q)) -> A-frag of PV-mfma
//   Softmax denominator: VALU adds + shfl_xor(16,32); normalization uses
//   shfl to fetch 1/sum per q-row. AO written bf16 [b=(n0,w)][s][c].
// K2 (proj): bf16 MFMA 16x16x32, LDS-free (unchanged).

typedef __attribute__((ext_vector_type(4))) float f32x4;
typedef __attribute__((ext_vector_type(4))) _Float16 f16x4;
typedef __attribute__((ext_vector_type(8))) short bf16x8;

__device__ __forceinline__ unsigned int bf16_rne(float x) {
    unsigned int u = __float_as_uint(x);
    return (u + 0x7fffu + ((u >> 16) & 1u)) >> 16;
}

__global__ void axattn_prep(const float* __restrict__ Wo,
                            unsigned short* __restrict__ Wob) {
    int i = blockIdx.x * 256 + threadIdx.x;   // 64 blocks * 256 = 16384
    Wob[i] = (unsigned short)bf16_rne(Wo[i]);
}

__global__ __launch_bounds__(256) void axattn_attn(
    const float* __restrict__ x,
    const float* __restrict__ Wq,
    const float* __restrict__ Wk,
    const float* __restrict__ Wv,
    unsigned short* __restrict__ AO)   // bf16 [(n0*128+w)][s][c]
{
    // bb = k*8 + xcd ; k = (n0*8+h)*4 + wg ; w = xcd*16 + wg*4 + wave
    // 4 consecutive-k blocks on one XCD cover a 16-w line group (L2 reuse).
    int bb  = blockIdx.x;
    int xcd = bb & 7;
    int kk  = bb >> 3;         // 0..255
    int wg  = kk & 3;
    int nh  = kk >> 2;         // n0*8 + h
    int n0  = nh >> 3;
    int h   = nh & 7;
    int wvi = threadIdx.x >> 6;   // wave 0..3 -> own problem
    int l   = threadIdx.x & 63;
    int lr  = l & 15;          // fragment row/col index
    int lg  = l >> 4;          // fragment k-group
    int w   = xcd * 16 + wg * 4 + wvi;

    const float qsc = 0.088388347648318447f * 1.4426950408889634f; // 1/sqrt(128)*log2e
    const f32x4 zf = {0.f, 0.f, 0.f, 0.f};

    // Weight fragments: lane reads W[lr][lg*4 .. +3] (one float4 each).
    float4 wqf = *(const float4*)(Wq + lr * 16 + lg * 4);
    float4 wkf = *(const float4*)(Wk + lr * 16 + lg * 4);
    float4 wvf = *(const float4*)(Wv + lr * 16 + lg * 4);
    f16x4 fq = {(_Float16)wqf.x, (_Float16)wqf.y, (_Float16)wqf.z, (_Float16)wqf.w};
    f16x4 fk = {(_Float16)wkf.x, (_Float16)wkf.y, (_Float16)wkf.z, (_Float16)wkf.w};
    f16x4 fv = {(_Float16)wvf.x, (_Float16)wvf.y, (_Float16)wvf.z, (_Float16)wvf.w};

    // y fragments: yf[rt][j] = y[rt*16+lr][lg*4+j]
    //            = x[n0*128 + h*16 + lg*4 + j][rt*16 + lr][w]
    const float* xb = x + ((size_t)(n0 * 128 + h * 16 + lg * 4) * 128 + lr) * 128 + w;
    f16x4 yf[8];
    #pragma unroll
    for (int rt = 0; rt < 8; ++rt) {
        float y0 = xb[rt * 2048];
        float y1 = xb[rt * 2048 + 16384];
        float y2 = xb[rt * 2048 + 32768];
        float y3 = xb[rt * 2048 + 49152];
        yf[rt] = (f16x4){(_Float16)y0, (_Float16)y1, (_Float16)y2, (_Float16)y3};
    }

    // Projections: per 16-row tile t.
    f16x4 qb[8], ka[8], vb[8];
    #pragma unroll
    for (int t = 0; t < 8; ++t) {
        f32x4 qt = __builtin_amdgcn_mfma_f32_16x16x16f16(fq, yf[t], zf, 0, 0, 0);
        f32x4 kt = __builtin_amdgcn_mfma_f32_16x16x16f16(fk, yf[t], zf, 0, 0, 0);
        f32x4 vt = __builtin_amdgcn_mfma_f32_16x16x16f16(yf[t], fv, zf, 0, 0, 0);
        qb[t] = (f16x4){(_Float16)(qt[0] * qsc), (_Float16)(qt[1] * qsc),
                        (_Float16)(qt[2] * qsc), (_Float16)(qt[3] * qsc)};
        ka[t] = (f16x4){(_Float16)kt[0], (_Float16)kt[1], (_Float16)kt[2], (_Float16)kt[3]};
        vb[t] = (f16x4){(_Float16)vt[0], (_Float16)vt[1], (_Float16)vt[2], (_Float16)vt[3]};
    }

    // AO base for this lane: row q = qt*16 + lg*4 + r, col c = h*16 + lr.
    unsigned short* aob = AO + ((size_t)(n0 * 128 + w) * 128 + lg * 4) * 128 + h * 16 + lr;

    #pragma unroll
    for (int qt = 0; qt < 8; ++qt) {
        // S tiles: lane holds energy[q=lr][key = kt*16 + lg*4 + r] (Q pre-scaled).
        f32x4 s[8];
        #pragma unroll
        for (int kt = 0; kt < 8; ++kt)
            s[kt] = __builtin_amdgcn_mfma_f32_16x16x16f16(ka[kt], qb[qt], zf, 0, 0, 0);
        float sum = 0.f;
        f16x4 pa[8];
        #pragma unroll
        for (int kt = 0; kt < 8; ++kt) {
            float p0 = __builtin_amdgcn_exp2f(s[kt][0]);
            float p1 = __builtin_amdgcn_exp2f(s[kt][1]);
            float p2 = __builtin_amdgcn_exp2f(s[kt][2]);
            float p3 = __builtin_amdgcn_exp2f(s[kt][3]);
            sum += (p0 + p1) + (p2 + p3);
            pa[kt] = (f16x4){(_Float16)p0, (_Float16)p1, (_Float16)p2, (_Float16)p3};
        }
        // full key-sum for column q=lr (4 lane-groups hold disjoint key subsets)
        sum += __shfl_xor(sum, 16);
        sum += __shfl_xor(sum, 32);
        // PV: O[q = qt*16 + lg*4 + r][d = lr]
        f32x4 o = zf;
        #pragma unroll
        for (int kt = 0; kt < 8; ++kt)
            o = __builtin_amdgcn_mfma_f32_16x16x16f16(pa[kt], vb[kt], o, 0, 0, 0);
        float rl = 1.f / sum;      // valid for q-column lr
        #pragma unroll
        for (int r = 0; r < 4; ++r) {
            float rs = __shfl(rl, lg * 4 + r);   // 1/sum for q-row lg*4+r
            aob[((size_t)qt * 16 + r) * 128] = (unsigned short)bf16_rne(o[r] * rs);
        }
    }
}

// MFMA out-proj (unchanged). Block = (n0, s, w-half). 4 waves; wave wv owns
// e-tile [wv*32,+32) x w-tile [wh*64,+64). m=e, n=w, k=c.
__global__ __launch_bounds__(256) void axattn_proj(
    const unsigned short* __restrict__ AOb,
    const unsigned short* __restrict__ Wob,
    const float* __restrict__ bo,
    float* __restrict__ out)
{
    int bb = blockIdx.x;
    int wh = bb & 1;
    int s  = (bb >> 1) & 127;
    int n0 = bb >> 8;
    int wv = threadIdx.x >> 6;
    int l  = threadIdx.x & 63;
    int lr = l & 15;
    int lk = (l >> 4) * 8;
    int eb = wv * 32;

    f32x4 acc[2][4];
    #pragma unroll
    for (int mi = 0; mi < 2; ++mi)
        #pragma unroll
        for (int ni = 0; ni < 4; ++ni)
            acc[mi][ni] = (f32x4){0.f, 0.f, 0.f, 0.f};

    const unsigned short* wp = Wob + (size_t)(eb + lr) * 128 + lk;
    const unsigned short* ap = AOb
        + ((size_t)(n0 * 128 + wh * 64 + lr) * 128 + s) * 128 + lk;

    #pragma unroll
    for (int ct = 0; ct < 4; ++ct) {             // k = c tile of 32
        bf16x8 a0 = *(const bf16x8*)(wp + ct * 32);
        bf16x8 a1 = *(const bf16x8*)(wp + 16 * 128 + ct * 32);
        #pragma unroll
        for (int ni = 0; ni < 4; ++ni) {
            bf16x8 bf = *(const bf16x8*)(ap + (size_t)ni * 262144 + ct * 32);
            acc[0][ni] = __builtin_amdgcn_mfma_f32_16x16x32_bf16(a0, bf, acc[0][ni], 0, 0, 0);
            acc[1][ni] = __builtin_amdgcn_mfma_f32_16x16x32_bf16(a1, bf, acc[1][ni], 0, 0, 0);
        }
    }

    int r4 = (l >> 4) * 4;
    #pragma unroll
    for (int mi = 0; mi < 2; ++mi) {
        #pragma unroll
        for (int r = 0; r < 4; ++r) {
            int e = eb + mi * 16 + r4 + r;
            float bv = bo[e];
            float* orow = out + ((size_t)(n0 * 128 + e) * 128 + s) * 128 + wh * 64 + lr;
            #pragma unroll
            for (int ni = 0; ni < 4; ++ni)
                orow[ni * 16] = acc[mi][ni][r] + bv;
        }
    }
}

extern "C" void kernel_launch(void* const* d_in, const int* in_sizes, int n_in,
                              void* d_out, int out_size, void* d_ws, size_t ws_size,
                              hipStream_t stream) {
    const float* x  = (const float*)d_in[0];
    const float* Wq = (const float*)d_in[1];
    const float* Wk = (const float*)d_in[2];
    const float* Wv = (const float*)d_in[3];
    const float* Wo = (const float*)d_in[4];
    const float* bo = (const float*)d_in[5];
    float* out = (float*)d_out;

    unsigned short* AOb = (unsigned short*)d_ws;                        // 32 MiB bf16
    unsigned short* Wob = (unsigned short*)((char*)d_ws + (32u << 20)); // 32 KiB bf16

    axattn_prep<<<64, 256, 0, stream>>>(Wo, Wob);
    axattn_attn<<<2048, 256, 0, stream>>>(x, Wq, Wk, Wv, AOb);
    axattn_proj<<<2048, 256, 0, stream>>>(AOb, Wob, bo, out);
}

// Round 4
// 158.190 us; speedup vs baseline: 2.4664x; 1.2681x over previous
//
#include <hip/hip_runtime.h>
#include <hip/hip_fp16.h>

// AxialAttention on MI355X (gfx950).
// x: [8,128,128,128] fp32, attend along H. Problem = (n0,h,w): S=128, d=16.
// K1 (attn): fully-MFMA. x-tile staged to LDS as f16 via coalesced float4
//   loads (w contiguous), y-fragments via ds_read_b64. Fragment chain
//   (D==A/B layout identity of 16x16x16 MFMA):
//     Q^T = mfma(Wq, y^T) (scaled by 1/sqrt(128)*log2e), K^T = mfma(Wk, y^T),
//     V = mfma(y, Wv^T), P^T = exp2(mfma(K, Q)), O = mfma(P, V).
//   AO written bf16 [b=(n0,w)][s][c].
// K2 (proj): block=(n0,s). AO tile (128w x 128c bf16 = 32KB) staged to LDS
//   once (coalesced, single-pass, kills the 32KiB-stride L1 alias of v1),
//   4 waves x (32e x 128w) via 16x16x32 bf16 MFMA, Wo A-frags from L1.

typedef __attribute__((ext_vector_type(4))) float f32x4;
typedef __attribute__((ext_vector_type(4))) _Float16 f16x4;
typedef __attribute__((ext_vector_type(8))) short bf16x8;

__device__ __forceinline__ unsigned int bf16_rne(float x) {
    unsigned int u = __float_as_uint(x);
    return (u + 0x7fffu + ((u >> 16) & 1u)) >> 16;
}
__device__ __forceinline__ unsigned int pack_half2(float a, float b) {
    __half2 h = __floats2half2_rn(a, b);
    return *reinterpret_cast<unsigned int*>(&h);
}

__global__ void axattn_prep(const float* __restrict__ Wo,
                            unsigned short* __restrict__ Wob) {
    int i = blockIdx.x * 256 + threadIdx.x;   // 64 blocks * 256 = 16384
    Wob[i] = (unsigned short)bf16_rne(Wo[i]);
}

__global__ __launch_bounds__(256) void axattn_attn(
    const float* __restrict__ x,
    const float* __restrict__ Wq,
    const float* __restrict__ Wk,
    const float* __restrict__ Wv,
    unsigned short* __restrict__ AO)   // bf16 [(n0*128+w)][s][c]
{
    // bb = k*8 + xcd ; k = (n0*8+h)*4 + wg ; w = xcd*16 + wg*4 + wave
    int bb  = blockIdx.x;
    int xcd = bb & 7;
    int kk  = bb >> 3;         // 0..255
    int wg  = kk & 3;
    int nh  = kk >> 2;         // n0*8 + h
    int n0  = nh >> 3;
    int h   = nh & 7;
    int tid = threadIdx.x;
    int wvi = tid >> 6;        // wave 0..3 -> own problem (w)
    int l   = tid & 63;
    int lr  = l & 15;          // fragment row/col index
    int lg  = l >> 4;          // fragment k-group
    int w0  = xcd * 16 + wg * 4;
    int w   = w0 + wvi;

    // x-tile as f16: [w][row][c2] ; row stride 10 u32 (40B: 32B data + 8 pad)
    __shared__ unsigned int xs[4 * 1280];

    #pragma unroll
    for (int it = 0; it < 4; ++it) {
        int pid = it * 256 + tid;      // 0..1023
        int c2  = pid >> 7;            // c-pair 0..7
        int row = pid & 127;
        const float* gp = x + ((size_t)(n0 * 128 + h * 16 + 2 * c2) * 128 + row) * 128 + w0;
        float4 va = *(const float4*)gp;            // c = 2*c2,   w0..w0+3
        float4 vb = *(const float4*)(gp + 16384);  // c = 2*c2+1, w0..w0+3
        unsigned int* dp = xs + row * 10 + c2;
        dp[0]    = pack_half2(va.x, vb.x);
        dp[1280] = pack_half2(va.y, vb.y);
        dp[2560] = pack_half2(va.z, vb.z);
        dp[3840] = pack_half2(va.w, vb.w);
    }

    const float qsc = 0.088388347648318447f * 1.4426950408889634f; // 1/sqrt(128)*log2e
    const f32x4 zf = {0.f, 0.f, 0.f, 0.f};

    // Weight fragments: lane reads W[lr][lg*4 .. +3].
    float4 wqf = *(const float4*)(Wq + lr * 16 + lg * 4);
    float4 wkf = *(const float4*)(Wk + lr * 16 + lg * 4);
    float4 wvf = *(const float4*)(Wv + lr * 16 + lg * 4);
    f16x4 fq = {(_Float16)wqf.x, (_Float16)wqf.y, (_Float16)wqf.z, (_Float16)wqf.w};
    f16x4 fk = {(_Float16)wkf.x, (_Float16)wkf.y, (_Float16)wkf.z, (_Float16)wkf.w};
    f16x4 fv = {(_Float16)wvf.x, (_Float16)wvf.y, (_Float16)wvf.z, (_Float16)wvf.w};

    __syncthreads();

    // y fragments from LDS: yf[rt][j] = y[rt*16+lr][lg*4+j]
    const char* yb = (const char*)xs + wvi * 5120 + lr * 40 + lg * 8;
    f16x4 yf[8];
    #pragma unroll
    for (int rt = 0; rt < 8; ++rt)
        yf[rt] = *(const f16x4*)(yb + rt * 640);   // 16 rows * 40B

    // Projections: per 16-row tile t.
    f16x4 qb[8], ka[8], vb[8];
    #pragma unroll
    for (int t = 0; t < 8; ++t) {
        f32x4 qt = __builtin_amdgcn_mfma_f32_16x16x16f16(fq, yf[t], zf, 0, 0, 0);
        f32x4 kt = __builtin_amdgcn_mfma_f32_16x16x16f16(fk, yf[t], zf, 0, 0, 0);
        f32x4 vt = __builtin_amdgcn_mfma_f32_16x16x16f16(yf[t], fv, zf, 0, 0, 0);
        qb[t] = (f16x4){(_Float16)(qt[0] * qsc), (_Float16)(qt[1] * qsc),
                        (_Float16)(qt[2] * qsc), (_Float16)(qt[3] * qsc)};
        ka[t] = (f16x4){(_Float16)kt[0], (_Float16)kt[1], (_Float16)kt[2], (_Float16)kt[3]};
        vb[t] = (f16x4){(_Float16)vt[0], (_Float16)vt[1], (_Float16)vt[2], (_Float16)vt[3]};
    }

    // AO base for this lane: row q = qt*16 + lg*4 + r, col c = h*16 + lr.
    unsigned short* aob = AO + ((size_t)(n0 * 128 + w) * 128 + lg * 4) * 128 + h * 16 + lr;

    #pragma unroll
    for (int qt = 0; qt < 8; ++qt) {
        f32x4 s[8];
        #pragma unroll
        for (int kt = 0; kt < 8; ++kt)
            s[kt] = __builtin_amdgcn_mfma_f32_16x16x16f16(ka[kt], qb[qt], zf, 0, 0, 0);
        float sum = 0.f;
        f16x4 pa[8];
        #pragma unroll
        for (int kt = 0; kt < 8; ++kt) {
            float p0 = __builtin_amdgcn_exp2f(s[kt][0]);
            float p1 = __builtin_amdgcn_exp2f(s[kt][1]);
            float p2 = __builtin_amdgcn_exp2f(s[kt][2]);
            float p3 = __builtin_amdgcn_exp2f(s[kt][3]);
            sum += (p0 + p1) + (p2 + p3);
            pa[kt] = (f16x4){(_Float16)p0, (_Float16)p1, (_Float16)p2, (_Float16)p3};
        }
        sum += __shfl_xor(sum, 16);
        sum += __shfl_xor(sum, 32);
        f32x4 o = zf;
        #pragma unroll
        for (int kt = 0; kt < 8; ++kt)
            o = __builtin_amdgcn_mfma_f32_16x16x16f16(pa[kt], vb[kt], o, 0, 0, 0);
        float rl = 1.f / sum;      // valid for q-column lr
        #pragma unroll
        for (int r = 0; r < 4; ++r) {
            float rs = __shfl(rl, lg * 4 + r);   // 1/sum for q-row lg*4+r
            aob[((size_t)qt * 16 + r) * 128] = (unsigned short)bf16_rne(o[r] * rs);
        }
    }
}

// MFMA out-proj v2. Block = (n0, s); AO tile staged to LDS once; 4 waves,
// wave wv: e-tile [wv*32,+32) x full w 0..127. m=e, n=w, k=c.
__global__ __launch_bounds__(256) void axattn_proj(
    const unsigned short* __restrict__ AOb,
    const unsigned short* __restrict__ Wob,
    const float* __restrict__ bo,
    float* __restrict__ out)
{
    int bb  = blockIdx.x;
    int n0  = bb >> 7;
    int s   = bb & 127;
    int tid = threadIdx.x;
    int wv  = tid >> 6;
    int l   = tid & 63;
    int lr  = l & 15;
    int lg  = l >> 4;
    int lk  = lg * 8;
    int eb  = wv * 32;

    // AO tile [w-row 0..127][c 0..127] bf16, row stride 272B (256B + 16 pad)
    __shared__ char as_[128 * 272];

    #pragma unroll
    for (int it = 0; it < 8; ++it) {
        int flat = it * 256 + tid;     // 0..2047
        int row  = flat >> 4;
        int seg  = flat & 15;
        const uint4* src = (const uint4*)(AOb + ((size_t)(n0 * 128 + row) * 128 + s) * 128) + seg;
        *(uint4*)(as_ + row * 272 + seg * 16) = *src;
    }
    __syncthreads();

    f32x4 acc[2][8];
    #pragma unroll
    for (int mi = 0; mi < 2; ++mi)
        #pragma unroll
        for (int ni = 0; ni < 8; ++ni)
            acc[mi][ni] = (f32x4){0.f, 0.f, 0.f, 0.f};

    const unsigned short* wp = Wob + (size_t)(eb + lr) * 128 + lk;

    #pragma unroll
    for (int ct = 0; ct < 4; ++ct) {             // k = c tile of 32
        bf16x8 a0 = *(const bf16x8*)(wp + ct * 32);
        bf16x8 a1 = *(const bf16x8*)(wp + 16 * 128 + ct * 32);
        #pragma unroll
        for (int ni = 0; ni < 8; ++ni) {
            bf16x8 b = *(const bf16x8*)(as_ + (ni * 16 + lr) * 272 + (lk + ct * 32) * 2);
            acc[0][ni] = __builtin_amdgcn_mfma_f32_16x16x32_bf16(a0, b, acc[0][ni], 0, 0, 0);
            acc[1][ni] = __builtin_amdgcn_mfma_f32_16x16x32_bf16(a1, b, acc[1][ni], 0, 0, 0);
        }
    }

    int r4 = lg * 4;
    #pragma unroll
    for (int mi = 0; mi < 2; ++mi) {
        #pragma unroll
        for (int r = 0; r < 4; ++r) {
            int e = eb + mi * 16 + r4 + r;
            float bv = bo[e];
            float* orow = out + ((size_t)(n0 * 128 + e) * 128 + s) * 128 + lr;
            #pragma unroll
            for (int ni = 0; ni < 8; ++ni)
                orow[ni * 16] = acc[mi][ni][r] + bv;
        }
    }
}

extern "C" void kernel_launch(void* const* d_in, const int* in_sizes, int n_in,
                              void* d_out, int out_size, void* d_ws, size_t ws_size,
                              hipStream_t stream) {
    const float* x  = (const float*)d_in[0];
    const float* Wq = (const float*)d_in[1];
    const float* Wk = (const float*)d_in[2];
    const float* Wv = (const float*)d_in[3];
    const float* Wo = (const float*)d_in[4];
    const float* bo = (const float*)d_in[5];
    float* out = (float*)d_out;

    unsigned short* AOb = (unsigned short*)d_ws;                        // 32 MiB bf16
    unsigned short* Wob = (unsigned short*)((char*)d_ws + (32u << 20)); // 32 KiB bf16

    axattn_prep<<<64, 256, 0, stream>>>(Wo, Wob);
    axattn_attn<<<2048, 256, 0, stream>>>(x, Wq, Wk, Wv, AOb);
    axattn_proj<<<1024, 256, 0, stream>>>(AOb, Wob, bo, out);
}

// Round 5
// 154.723 us; speedup vs baseline: 2.5216x; 1.0224x over previous
//
#include <hip/hip_runtime.h>
#include <hip/hip_fp16.h>

// AxialAttention on MI355X (gfx950).
// x: [8,128,128,128] fp32, attend along H. Problem = (n0,h,w): S=128, d=16.
// K1 (attn): fully-MFMA. Block = 512 thr / 8 waves, owns 8 consecutive w
//   (1 problem per wave). x-tile staged to LDS as f16 with lane-pairs covering
//   32B-contiguous global segments (paired wp-blocks on same XCD take the
//   other half-line from L2). Fragment chain (D==A/B layout identity of
//   16x16x16 MFMA):
//     Q^T = mfma(Wq, y^T) (scaled by 1/sqrt(128)*log2e), K^T = mfma(Wk, y^T),
//     V = mfma(y, Wv^T), P^T = exp2(mfma(K, Q)), O = mfma(P, V)  (2 chains).
//   AO written bf16 [b=(n0,w)][s][c].
// K2 (proj): block=(n0,s,w-half). Wo A-frags preloaded to regs, then AO
//   half-tile (64w x 128c bf16 = 16KB+pad) staged to LDS (coalesced),
//   4 waves x (32e x 64w) via 16x16x32 bf16 MFMA.

typedef __attribute__((ext_vector_type(4))) float f32x4;
typedef __attribute__((ext_vector_type(4))) _Float16 f16x4;
typedef __attribute__((ext_vector_type(8))) short bf16x8;

__device__ __forceinline__ unsigned int bf16_rne(float x) {
    unsigned int u = __float_as_uint(x);
    return (u + 0x7fffu + ((u >> 16) & 1u)) >> 16;
}
__device__ __forceinline__ unsigned int pack_half2(float a, float b) {
    __half2 h = __floats2half2_rn(a, b);
    return *reinterpret_cast<unsigned int*>(&h);
}

__global__ void axattn_prep(const float* __restrict__ Wo,
                            unsigned short* __restrict__ Wob) {
    int i = blockIdx.x * 256 + threadIdx.x;   // 64 blocks * 256 = 16384
    Wob[i] = (unsigned short)bf16_rne(Wo[i]);
}

__global__ __launch_bounds__(512) void axattn_attn(
    const float* __restrict__ x,
    const float* __restrict__ Wq,
    const float* __restrict__ Wk,
    const float* __restrict__ Wv,
    unsigned short* __restrict__ AO)   // bf16 [(n0*128+w)][s][c]
{
    // bb = ((n0*8+h)*2 + wp)*8 + xcd ; w0 = xcd*16 + wp*8 ; wave wvi: w = w0+wvi
    // wp-pair blocks (bb, bb+8) land on the same XCD -> share x cache lines.
    int bb  = blockIdx.x;
    int xcd = bb & 7;
    int t2  = bb >> 3;         // (n0*8+h)*2 + wp
    int wp  = t2 & 1;
    int nh  = t2 >> 1;         // n0*8 + h
    int n0  = nh >> 3;
    int h   = nh & 7;
    int tid = threadIdx.x;
    int wvi = tid >> 6;        // wave 0..7 -> own problem (w)
    int l   = tid & 63;
    int lr  = l & 15;          // fragment row/col index
    int lg  = l >> 4;          // fragment k-group
    int w0  = xcd * 16 + wp * 8;
    int w   = w0 + wvi;

    // x-tile as f16: [w-local 0..7][row][c2] ; row stride 10 u32 (40B)
    __shared__ unsigned int xs[8 * 1280];

    // Staging: thread -> (q = w-quad 0/1, row, c2 base); 4 c2 per thread.
    // Per wave-instr: lane pairs (q=0,1) cover 32B contiguous; 32 rows.
    {
        int q   = tid & 1;
        int row = (tid >> 1) & 127;
        int c2b = tid >> 8;    // 0/1
        const float* gp0 = x + ((size_t)(n0 * 128 + h * 16) * 128 + row) * 128 + w0 + q * 4;
        #pragma unroll
        for (int it = 0; it < 4; ++it) {
            int c2 = it * 2 + c2b;
            const float* gp = gp0 + (size_t)(2 * c2) * 16384;
            float4 va = *(const float4*)gp;            // c = 2*c2
            float4 vb = *(const float4*)(gp + 16384);  // c = 2*c2+1
            unsigned int* dp = xs + (q * 4) * 1280 + row * 10 + c2;
            dp[0]    = pack_half2(va.x, vb.x);
            dp[1280] = pack_half2(va.y, vb.y);
            dp[2560] = pack_half2(va.z, vb.z);
            dp[3840] = pack_half2(va.w, vb.w);
        }
    }

    const float qsc = 0.088388347648318447f * 1.4426950408889634f; // 1/sqrt(128)*log2e
    const f32x4 zf = {0.f, 0.f, 0.f, 0.f};

    // Weight fragments: lane reads W[lr][lg*4 .. +3] (overlaps staging).
    float4 wqf = *(const float4*)(Wq + lr * 16 + lg * 4);
    float4 wkf = *(const float4*)(Wk + lr * 16 + lg * 4);
    float4 wvf = *(const float4*)(Wv + lr * 16 + lg * 4);
    f16x4 fq = {(_Float16)wqf.x, (_Float16)wqf.y, (_Float16)wqf.z, (_Float16)wqf.w};
    f16x4 fk = {(_Float16)wkf.x, (_Float16)wkf.y, (_Float16)wkf.z, (_Float16)wkf.w};
    f16x4 fv = {(_Float16)wvf.x, (_Float16)wvf.y, (_Float16)wvf.z, (_Float16)wvf.w};

    __syncthreads();

    // y fragments from LDS: yf[rt][j] = y[rt*16+lr][lg*4+j]
    const char* yb = (const char*)xs + wvi * 5120 + lr * 40 + lg * 8;
    f16x4 yf[8];
    #pragma unroll
    for (int rt = 0; rt < 8; ++rt)
        yf[rt] = *(const f16x4*)(yb + rt * 640);   // 16 rows * 40B

    // Projections: per 16-row tile t.
    f16x4 qb[8], ka[8], vb[8];
    #pragma unroll
    for (int t = 0; t < 8; ++t) {
        f32x4 qt = __builtin_amdgcn_mfma_f32_16x16x16f16(fq, yf[t], zf, 0, 0, 0);
        f32x4 kt = __builtin_amdgcn_mfma_f32_16x16x16f16(fk, yf[t], zf, 0, 0, 0);
        f32x4 vt = __builtin_amdgcn_mfma_f32_16x16x16f16(yf[t], fv, zf, 0, 0, 0);
        qb[t] = (f16x4){(_Float16)(qt[0] * qsc), (_Float16)(qt[1] * qsc),
                        (_Float16)(qt[2] * qsc), (_Float16)(qt[3] * qsc)};
        ka[t] = (f16x4){(_Float16)kt[0], (_Float16)kt[1], (_Float16)kt[2], (_Float16)kt[3]};
        vb[t] = (f16x4){(_Float16)vt[0], (_Float16)vt[1], (_Float16)vt[2], (_Float16)vt[3]};
    }

    // AO base for this lane: row q = qt*16 + lg*4 + r, col c = h*16 + lr.
    unsigned short* aob = AO + ((size_t)(n0 * 128 + w) * 128 + lg * 4) * 128 + h * 16 + lr;

    #pragma unroll
    for (int qt = 0; qt < 8; ++qt) {
        f32x4 s[8];
        #pragma unroll
        for (int kt = 0; kt < 8; ++kt)
            s[kt] = __builtin_amdgcn_mfma_f32_16x16x16f16(ka[kt], qb[qt], zf, 0, 0, 0);
        float sum = 0.f;
        f16x4 pa[8];
        #pragma unroll
        for (int kt = 0; kt < 8; ++kt) {
            float p0 = __builtin_amdgcn_exp2f(s[kt][0]);
            float p1 = __builtin_amdgcn_exp2f(s[kt][1]);
            float p2 = __builtin_amdgcn_exp2f(s[kt][2]);
            float p3 = __builtin_amdgcn_exp2f(s[kt][3]);
            sum += (p0 + p1) + (p2 + p3);
            pa[kt] = (f16x4){(_Float16)p0, (_Float16)p1, (_Float16)p2, (_Float16)p3};
        }
        sum += __shfl_xor(sum, 16);
        sum += __shfl_xor(sum, 32);
        // PV as two independent 4-deep chains (halves serial MFMA latency)
        f32x4 oA = zf, oB = zf;
        #pragma unroll
        for (int kt = 0; kt < 4; ++kt) {
            oA = __builtin_amdgcn_mfma_f32_16x16x16f16(pa[kt],     vb[kt],     oA, 0, 0, 0);
            oB = __builtin_amdgcn_mfma_f32_16x16x16f16(pa[kt + 4], vb[kt + 4], oB, 0, 0, 0);
        }
        f32x4 o = oA + oB;
        float rl = 1.f / sum;      // valid for q-column lr
        #pragma unroll
        for (int r = 0; r < 4; ++r) {
            float rs = __shfl(rl, lg * 4 + r);   // 1/sum for q-row lg*4+r
            aob[((size_t)qt * 16 + r) * 128] = (unsigned short)bf16_rne(o[r] * rs);
        }
    }
}

// MFMA out-proj v3. Block = (n0, s, w-half); Wo A-frags preloaded to regs,
// AO half-tile staged to LDS; 4 waves, wave wv: e-tile [wv*32,+32) x 64 w.
__global__ __launch_bounds__(256) void axattn_proj(
    const unsigned short* __restrict__ AOb,
    const unsigned short* __restrict__ Wob,
    const float* __restrict__ bo,
    float* __restrict__ out)
{
    int bb  = blockIdx.x;
    int wh  = bb & 1;
    int s   = (bb >> 1) & 127;
    int n0  = bb >> 8;
    int tid = threadIdx.x;
    int wv  = tid >> 6;
    int l   = tid & 63;
    int lr  = l & 15;
    int lg  = l >> 4;
    int lk  = lg * 8;
    int eb  = wv * 32;

    // AO half-tile [w-row 0..63][c 0..127] bf16, row stride 272B (256 + 16 pad)
    __shared__ char as_[64 * 272];

    // A-frags first: global loads overlap the LDS staging below.
    const unsigned short* wp_ = Wob + (size_t)(eb + lr) * 128 + lk;
    bf16x8 a0[4], a1[4];
    #pragma unroll
    for (int ct = 0; ct < 4; ++ct) {
        a0[ct] = *(const bf16x8*)(wp_ + ct * 32);
        a1[ct] = *(const bf16x8*)(wp_ + 16 * 128 + ct * 32);
    }

    #pragma unroll
    for (int it = 0; it < 4; ++it) {
        int flat = it * 256 + tid;     // 0..1023
        int row  = flat >> 4;          // 0..63
        int seg  = flat & 15;
        const uint4* src = (const uint4*)(AOb
            + ((size_t)(n0 * 128 + wh * 64 + row) * 128 + s) * 128) + seg;
        *(uint4*)(as_ + row * 272 + seg * 16) = *src;
    }
    __syncthreads();

    f32x4 acc[2][4];
    #pragma unroll
    for (int mi = 0; mi < 2; ++mi)
        #pragma unroll
        for (int ni = 0; ni < 4; ++ni)
            acc[mi][ni] = (f32x4){0.f, 0.f, 0.f, 0.f};

    #pragma unroll
    for (int ct = 0; ct < 4; ++ct) {             // k = c tile of 32
        #pragma unroll
        for (int ni = 0; ni < 4; ++ni) {
            bf16x8 b = *(const bf16x8*)(as_ + (ni * 16 + lr) * 272 + (lk + ct * 32) * 2);
            acc[0][ni] = __builtin_amdgcn_mfma_f32_16x16x32_bf16(a0[ct], b, acc[0][ni], 0, 0, 0);
            acc[1][ni] = __builtin_amdgcn_mfma_f32_16x16x32_bf16(a1[ct], b, acc[1][ni], 0, 0, 0);
        }
    }

    int r4 = lg * 4;
    #pragma unroll
    for (int mi = 0; mi < 2; ++mi) {
        #pragma unroll
        for (int r = 0; r < 4; ++r) {
            int e = eb + mi * 16 + r4 + r;
            float bv = bo[e];
            float* orow = out + ((size_t)(n0 * 128 + e) * 128 + s) * 128 + wh * 64 + lr;
            #pragma unroll
            for (int ni = 0; ni < 4; ++ni)
                orow[ni * 16] = acc[mi][ni][r] + bv;
        }
    }
}

extern "C" void kernel_launch(void* const* d_in, const int* in_sizes, int n_in,
                              void* d_out, int out_size, void* d_ws, size_t ws_size,
                              hipStream_t stream) {
    const float* x  = (const float*)d_in[0];
    const float* Wq = (const float*)d_in[1];
    const float* Wk = (const float*)d_in[2];
    const float* Wv = (const float*)d_in[3];
    const float* Wo = (const float*)d_in[4];
    const float* bo = (const float*)d_in[5];
    float* out = (float*)d_out;

    unsigned short* AOb = (unsigned short*)d_ws;                        // 32 MiB bf16
    unsigned short* Wob = (unsigned short*)((char*)d_ws + (32u << 20)); // 32 KiB bf16

    axattn_prep<<<64, 256, 0, stream>>>(Wo, Wob);
    axattn_attn<<<1024, 512, 0, stream>>>(x, Wq, Wk, Wv, AOb);
    axattn_proj<<<2048, 256, 0, stream>>>(AOb, Wob, bo, out);
}